// Round 2
// baseline (78.956 us; speedup 1.0000x reference)
//
#include <hip/hip_runtime.h>

#define BATCH   8
#define HW      (1024 * 1024)
#define NA      512
#define EPSV    1e-8f
#define LAML    0.01f
#define LAMS    0.01f

#define BPB      256                       // blocks per batch
#define NBLOCKS  (BATCH * BPB)             // 2048
#define PIXB     (HW / BPB)                // 4096 pixels per block
#define NVEC     (PIXB / 4)                // 1024 float4 per block
#define UNROLL   (NVEC / 256)              // 4 per thread

// Pass 1: per-(batch,admin) segment sums of score = (L+lamL)*(S+lamS).
__global__ __launch_bounds__(256) void k_sums(const float* __restrict__ lights,
                                              const float* __restrict__ settle,
                                              const int*   __restrict__ admin,
                                              float*       __restrict__ sums) {
    __shared__ float lsum[4][NA];          // one copy per wave
    const int tid = threadIdx.x;
    const int wid = tid >> 6;

    #pragma unroll
    for (int i = tid; i < 4 * NA; i += 256) ((float*)lsum)[i] = 0.0f;
    __syncthreads();

    const int b     = blockIdx.x / BPB;
    const int chunk = blockIdx.x % BPB;
    const long base = (long)b * HW + (long)chunk * PIXB;

    const float4* __restrict__ L4 = (const float4*)(lights + base);
    const float4* __restrict__ S4 = (const float4*)(settle + base);
    const int4*   __restrict__ A4 = (const int4*)(admin + base);

    float4 l[UNROLL], s[UNROLL];
    int4   a[UNROLL];
    #pragma unroll
    for (int u = 0; u < UNROLL; ++u) {
        const int v = tid + u * 256;
        l[u] = L4[v];
        s[u] = S4[v];
        a[u] = A4[v];
    }
    float* ls = lsum[wid];
    #pragma unroll
    for (int u = 0; u < UNROLL; ++u) {
        atomicAdd(&ls[a[u].x], (l[u].x + LAML) * (s[u].x + LAMS));
        atomicAdd(&ls[a[u].y], (l[u].y + LAML) * (s[u].y + LAMS));
        atomicAdd(&ls[a[u].z], (l[u].z + LAML) * (s[u].z + LAMS));
        atomicAdd(&ls[a[u].w], (l[u].w + LAML) * (s[u].w + LAMS));
    }
    __syncthreads();

    for (int i = tid; i < NA; i += 256) {
        float v = lsum[0][i] + lsum[1][i] + lsum[2][i] + lsum[3][i];
        if (v != 0.0f) atomicAdd(&sums[b * NA + i], v);
    }
}

// Pass 2: factor table per batch in LDS, recompute score, write out.
__global__ __launch_bounds__(256) void k_out(const float* __restrict__ lights,
                                             const float* __restrict__ settle,
                                             const int*   __restrict__ admin,
                                             const float* __restrict__ sums,
                                             const float* __restrict__ census,
                                             float*       __restrict__ out) {
    __shared__ float lfac[NA];
    const int tid = threadIdx.x;

    const int b     = blockIdx.x / BPB;
    const int chunk = blockIdx.x % BPB;

    for (int i = tid; i < NA; i += 256)
        lfac[i] = census[i] / (sums[b * NA + i] + EPSV);
    __syncthreads();

    const long base = (long)b * HW + (long)chunk * PIXB;
    const float4* __restrict__ L4 = (const float4*)(lights + base);
    const float4* __restrict__ S4 = (const float4*)(settle + base);
    const int4*   __restrict__ A4 = (const int4*)(admin + base);
    float4*       __restrict__ O4 = (float4*)(out + base);

    float4 l[UNROLL], s[UNROLL];
    int4   a[UNROLL];
    #pragma unroll
    for (int u = 0; u < UNROLL; ++u) {
        const int v = tid + u * 256;
        l[u] = L4[v];
        s[u] = S4[v];
        a[u] = A4[v];
    }
    #pragma unroll
    for (int u = 0; u < UNROLL; ++u) {
        float4 o;
        o.x = (l[u].x + LAML) * (s[u].x + LAMS) * lfac[a[u].x];
        o.y = (l[u].y + LAML) * (s[u].y + LAMS) * lfac[a[u].y];
        o.z = (l[u].z + LAML) * (s[u].z + LAMS) * lfac[a[u].z];
        o.w = (l[u].w + LAML) * (s[u].w + LAMS) * lfac[a[u].w];
        O4[tid + u * 256] = o;
    }
}

extern "C" void kernel_launch(void* const* d_in, const int* in_sizes, int n_in,
                              void* d_out, int out_size, void* d_ws, size_t ws_size,
                              hipStream_t stream) {
    const float* lights = (const float*)d_in[0];
    const float* settle = (const float*)d_in[1];
    const int*   admin  = (const int*)d_in[2];
    const float* census = (const float*)d_in[3];
    float*       out    = (float*)d_out;
    float*       sums   = (float*)d_ws;   // BATCH*NA floats

    // ws is poisoned (0xAA) and never re-poisoned between replays: zero it.
    hipMemsetAsync(sums, 0, BATCH * NA * sizeof(float), stream);

    k_sums<<<NBLOCKS, 256, 0, stream>>>(lights, settle, admin, sums);
    k_out<<<NBLOCKS, 256, 0, stream>>>(lights, settle, admin, sums, census, out);
}